// Round 1
// baseline (5832.346 us; speedup 1.0000x reference)
//
#include <hip/hip_runtime.h>
#include <stdint.h>

// ---------------------------------------------------------------------------
// TheoremProver on MI355X (gfx950).
// B=64, H=1024, S_AX=16384, NH=8, DH=128, STEPS=16.
// Key facts used:
//  * LSTM (wih/whh/bih/bhh) is dead code: h/c feed only themselves.  Skipped.
//  * Axiom K/V projection is loop-invariant: one big bf16 MFMA GEMM.
//  * Step-attention K/V are projections of frozen past states: project
//    incrementally (1 row-block per step) instead of re-projecting T rows.
//  * bf16 inputs / fp32 accumulate everywhere (harness threshold = bf16-tier).
// ---------------------------------------------------------------------------

typedef __attribute__((ext_vector_type(8))) short  bfx8;   // 8 x bf16 (4 VGPRs)
typedef __attribute__((ext_vector_type(4))) float  f32x4;

#define MFMA16(a, b, c) __builtin_amdgcn_mfma_f32_16x16x32_bf16((a), (b), (c), 0, 0, 0)

#define SCALE_QK 0.08838834764831845f  /* 1/sqrt(128) */

__device__ __forceinline__ unsigned short f2bf(float f) {
  union { float f; unsigned int u; } v; v.f = f;
  unsigned int r = (v.u + 0x7FFFu + ((v.u >> 16) & 1u)) >> 16;  // RNE
  return (unsigned short)r;
}

__device__ __forceinline__ float gelu_exact(float x) {
  return 0.5f * x * (1.0f + erff(x * 0.70710678118654752f));
}

__device__ __forceinline__ bfx8 ld8(const unsigned short* p) {
  return *reinterpret_cast<const bfx8*>(p);
}

// ---------------------------------------------------------------- fp32->bf16
__global__ __launch_bounds__(256) void cvt_bf16_k(const float* __restrict__ s,
                                                  unsigned short* __restrict__ d,
                                                  int n4) {
  int i = blockIdx.x * 256 + threadIdx.x;
  int stride = gridDim.x * 256;
  for (; i < n4; i += stride) {
    float4 v = reinterpret_cast<const float4*>(s)[i];
    ushort4 o;
    o.x = f2bf(v.x); o.y = f2bf(v.y); o.z = f2bf(v.z); o.w = f2bf(v.w);
    reinterpret_cast<ushort4*>(d)[i] = o;
  }
}

// ------------------------------------------------------------------ init
// conjecture -> d_out step slot 0 (fp32) and comb slot 0 (bf16 "state").
__global__ __launch_bounds__(256) void init_state_k(const float* __restrict__ conj,
                                                    float* __restrict__ out0,
                                                    unsigned short* __restrict__ comb) {
  int i = blockIdx.x * 256 + threadIdx.x;  // 65536 total
  float v = conj[i];
  out0[i] = v;
  int b = i >> 10, c = i & 1023;
  comb[b * 3072 + c] = f2bf(v);
}

// ---------------------------------------------------- axiom K/V projection
// C[16384, 2048] = axiom_emb[16384,1024] @ Wkv[2048,1024]^T + bias
// cols [0,1024) -> kp[s][c] bf16 ; cols [1024,2048) -> vpT[c-1024][s] bf16.
// 128x128 tile, BK=32, 4 waves (2x2), reg-staged LDS (padded stride 40).
__global__ __launch_bounds__(256) void kvproj_k(const float* __restrict__ aemb,
                                                const unsigned short* __restrict__ Wkv,
                                                const float* __restrict__ bias,
                                                unsigned short* __restrict__ kp,
                                                unsigned short* __restrict__ vpT) {
  __shared__ __align__(16) unsigned short Asl[128 * 40];
  __shared__ __align__(16) unsigned short Bsl[128 * 40];
  int m0 = blockIdx.x * 128, n0 = blockIdx.y * 128;
  int tid = threadIdx.x;
  int w = tid >> 6, l = tid & 63;
  int wm = w >> 1, wn = w & 1;
  int lane16 = l & 15, kg = l >> 4;
  int srow = tid >> 1, shalf = tid & 1;

  const float* Ag = aemb + (size_t)(m0 + srow) * 1024 + shalf * 16;
  const unsigned short* Bg = Wkv + (size_t)(n0 + srow) * 1024 + shalf * 16;
  unsigned short* As = &Asl[srow * 40 + shalf * 16];
  unsigned short* Bs = &Bsl[srow * 40 + shalf * 16];

  f32x4 acc[4][4];
  f32x4 zz = {0.f, 0.f, 0.f, 0.f};
#pragma unroll
  for (int a = 0; a < 4; a++)
#pragma unroll
    for (int b = 0; b < 4; b++) acc[a][b] = zz;

  for (int k0 = 0; k0 < 1024; k0 += 32) {
    float4 f0 = *(const float4*)(Ag + k0);
    float4 f1 = *(const float4*)(Ag + k0 + 4);
    float4 f2 = *(const float4*)(Ag + k0 + 8);
    float4 f3 = *(const float4*)(Ag + k0 + 12);
    ushort4 u0, u1, u2, u3;
    u0.x = f2bf(f0.x); u0.y = f2bf(f0.y); u0.z = f2bf(f0.z); u0.w = f2bf(f0.w);
    u1.x = f2bf(f1.x); u1.y = f2bf(f1.y); u1.z = f2bf(f1.z); u1.w = f2bf(f1.w);
    u2.x = f2bf(f2.x); u2.y = f2bf(f2.y); u2.z = f2bf(f2.z); u2.w = f2bf(f2.w);
    u3.x = f2bf(f3.x); u3.y = f2bf(f3.y); u3.z = f2bf(f3.z); u3.w = f2bf(f3.w);
    bfx8 b0 = ld8(Bg + k0);
    bfx8 b1 = ld8(Bg + k0 + 8);

    __syncthreads();  // previous compute done before overwrite
    *(ushort4*)(As + 0) = u0;
    *(ushort4*)(As + 4) = u1;
    *(ushort4*)(As + 8) = u2;
    *(ushort4*)(As + 12) = u3;
    *reinterpret_cast<bfx8*>(Bs) = b0;
    *reinterpret_cast<bfx8*>(Bs + 8) = b1;
    __syncthreads();

    bfx8 af[4], bfr[4];
#pragma unroll
    for (int mr = 0; mr < 4; mr++)
      af[mr] = *reinterpret_cast<const bfx8*>(&Asl[(wm * 64 + mr * 16 + lane16) * 40 + kg * 8]);
#pragma unroll
    for (int nr = 0; nr < 4; nr++)
      bfr[nr] = *reinterpret_cast<const bfx8*>(&Bsl[(wn * 64 + nr * 16 + lane16) * 40 + kg * 8]);
#pragma unroll
    for (int mr = 0; mr < 4; mr++)
#pragma unroll
      for (int nr = 0; nr < 4; nr++)
        acc[mr][nr] = MFMA16(af[mr], bfr[nr], acc[mr][nr]);
  }

#pragma unroll
  for (int mr = 0; mr < 4; mr++)
#pragma unroll
    for (int nr = 0; nr < 4; nr++) {
      int rowg0 = m0 + wm * 64 + mr * 16 + kg * 4;
      int colg = n0 + wn * 64 + nr * 16 + lane16;
      float bi = bias[colg];
#pragma unroll
      for (int r = 0; r < 4; r++) {
        float v = acc[mr][nr][r] + bi;
        unsigned short bv = f2bf(v);
        int rg = rowg0 + r;
        if (colg < 1024) kp[(size_t)rg * 1024 + colg] = bv;
        else             vpT[(size_t)(colg - 1024) * 16384 + rg] = bv;
      }
    }
}

// --------------------------------------------------------- generic M=64 GEMM
// out[64,N] = A[64,K]_bf16 @ W[N,K]_bf16^T + bias, fused epilogues.
// Block: 4 waves; wave w -> cols [n0+16w, n0+16w+16), all 4 row-tiles.
struct GemmP {
  const unsigned short* A; int lda;
  const unsigned short* W; int ldw;
  const float* bias;
  int K;
  int epi;            // 0 qa, 1 qskv-split, 2 bf16, 3 gelu->f32, 4 f32, 5 gen2
  float scale;
  unsigned short* out_bf; int ldo;
  float* out_f32; int ldo_f;
  float* qs; float* kc; float* vc;
};

__global__ __launch_bounds__(256) void gemm64_k(GemmP p) {
  int n0 = blockIdx.x * 64;
  int w = threadIdx.x >> 6, l = threadIdx.x & 63;
  int lane16 = l & 15, kg = l >> 4;
  int col = n0 + w * 16 + lane16;
  int lda = p.lda;
  const unsigned short* Wb = p.W + (size_t)col * p.ldw + kg * 8;
  const unsigned short* Ab = p.A + (size_t)lane16 * lda + kg * 8;

  f32x4 zz = {0.f, 0.f, 0.f, 0.f};
  f32x4 acc0 = zz, acc1 = zz, acc2 = zz, acc3 = zz;
#pragma unroll 4
  for (int k = 0; k < p.K; k += 32) {
    bfx8 bfr = ld8(Wb + k);
    acc0 = MFMA16(ld8(Ab + k), bfr, acc0);
    acc1 = MFMA16(ld8(Ab + 16 * lda + k), bfr, acc1);
    acc2 = MFMA16(ld8(Ab + 32 * lda + k), bfr, acc2);
    acc3 = MFMA16(ld8(Ab + 48 * lda + k), bfr, acc3);
  }
  float bi = p.bias[col];
  f32x4 accs[4] = {acc0, acc1, acc2, acc3};
#pragma unroll
  for (int mt = 0; mt < 4; ++mt) {
#pragma unroll
    for (int r = 0; r < 4; ++r) {
      int row = mt * 16 + kg * 4 + r;
      float v = accs[mt][r] + bi;
      switch (p.epi) {
        case 0:  // qa: (x+b)*scale -> bf16
          p.out_bf[(size_t)row * p.ldo + col] = f2bf(v * p.scale);
          break;
        case 1:  // qskv: split q (f32), k_new, v_new (f32 caches)
          if (col < 1024)       p.qs[row * 1024 + col] = v;
          else if (col < 2048)  p.kc[row * 1024 + col - 1024] = v;
          else                  p.vc[row * 1024 + col - 2048] = v;
          break;
        case 2:  // bf16 out (into comb slots)
          p.out_bf[(size_t)row * p.ldo + col] = f2bf(v);
          break;
        case 3:  // gelu -> f32 (validity hidden)
          p.out_f32[(size_t)row * p.ldo_f + col] = gelu_exact(v);
          break;
        case 4:  // f32 out (gen1 pre-LN)
          p.out_f32[(size_t)row * p.ldo_f + col] = v;
          break;
        case 5:  // gen2: f32 -> d_out step slot, bf16 -> comb slot 0
          p.out_f32[(size_t)row * p.ldo_f + col] = v;
          p.out_bf[(size_t)row * p.ldo + col] = f2bf(v);
          break;
      }
    }
  }
}

// ----------------------------------------------------- axiom attention pass1
// Per (head, 512-key chunk): flash partial (m, l, O[64,128]) with MFMA.
__global__ __launch_bounds__(256) void flash1_k(const unsigned short* __restrict__ qa,
                                                const unsigned short* __restrict__ kp,
                                                const unsigned short* __restrict__ vpT,
                                                float* __restrict__ Opart,
                                                float* __restrict__ mlpart) {
  int head = blockIdx.x >> 5;
  int chunk = blockIdx.x & 31;
  int w = threadIdx.x >> 6, l = threadIdx.x & 63;
  int lane16 = l & 15, kg = l >> 4;

  __shared__ __align__(16) unsigned short P_lds[64 * 72];
  __shared__ float alpha_lds[64];

  bfx8 qf[4];
  {
    const unsigned short* qb = qa + (size_t)(16 * w + lane16) * 1024 + head * 128 + kg * 8;
#pragma unroll
    for (int kk = 0; kk < 4; kk++) qf[kk] = ld8(qb + kk * 32);
  }
  float m_run[4], l_run[4];
#pragma unroll
  for (int r = 0; r < 4; r++) { m_run[r] = -__builtin_inff(); l_run[r] = 0.f; }
  f32x4 zz = {0.f, 0.f, 0.f, 0.f};
  f32x4 Oac[4][2];
#pragma unroll
  for (int mt = 0; mt < 4; mt++) { Oac[mt][0] = zz; Oac[mt][1] = zz; }

  for (int kb = 0; kb < 8; ++kb) {
    int key0 = chunk * 512 + kb * 64;
    // ---- scores: S[16 rows of this wave][64 keys]
    f32x4 sa[4] = {zz, zz, zz, zz};
#pragma unroll
    for (int kt = 0; kt < 4; kt++) {
      const unsigned short* kbp = kp + (size_t)(key0 + kt * 16 + lane16) * 1024 + head * 128 + kg * 8;
#pragma unroll
      for (int kk = 0; kk < 4; kk++) sa[kt] = MFMA16(qf[kk], ld8(kbp + kk * 32), sa[kt]);
    }
    __syncthreads();  // previous PV reads of P_lds complete
    // ---- online softmax update + write P
#pragma unroll
    for (int r = 0; r < 4; r++) {
      float mx = fmaxf(fmaxf(sa[0][r], sa[1][r]), fmaxf(sa[2][r], sa[3][r]));
#pragma unroll
      for (int m = 1; m < 16; m <<= 1) mx = fmaxf(mx, __shfl_xor(mx, m, 64));
      float mnew = fmaxf(m_run[r], mx);
      float al = expf(m_run[r] - mnew);
      int row = 16 * w + kg * 4 + r;
      float rs = 0.f;
#pragma unroll
      for (int kt = 0; kt < 4; kt++) {
        float pv = expf(sa[kt][r] - mnew);
        rs += pv;
        P_lds[row * 72 + kt * 16 + lane16] = f2bf(pv);
      }
#pragma unroll
      for (int m = 1; m < 16; m <<= 1) rs += __shfl_xor(rs, m, 64);
      l_run[r] = l_run[r] * al + rs;
      m_run[r] = mnew;
      if (lane16 == 0) alpha_lds[row] = al;
    }
    __syncthreads();
    // ---- rescale O, accumulate P@V (wave owns d-range [32w, 32w+32))
#pragma unroll
    for (int mt = 0; mt < 4; mt++)
#pragma unroll
      for (int r = 0; r < 4; r++) {
        float al = alpha_lds[mt * 16 + kg * 4 + r];
        Oac[mt][0][r] *= al;
        Oac[mt][1][r] *= al;
      }
    int d0 = w * 32;
#pragma unroll
    for (int ks = 0; ks < 2; ks++) {
      bfx8 pf[4];
#pragma unroll
      for (int mt = 0; mt < 4; mt++)
        pf[mt] = *reinterpret_cast<const bfx8*>(&P_lds[(mt * 16 + lane16) * 72 + ks * 32 + kg * 8]);
#pragma unroll
      for (int dt = 0; dt < 2; dt++) {
        int d = d0 + dt * 16 + lane16;
        bfx8 vf = ld8(vpT + (size_t)(head * 128 + d) * 16384 + key0 + ks * 32 + kg * 8);
#pragma unroll
        for (int mt = 0; mt < 4; mt++) Oac[mt][dt] = MFMA16(pf[mt], vf, Oac[mt][dt]);
      }
    }
  }
  // ---- write chunk partials
  float* mlb = mlpart + (size_t)(head * 32 + chunk) * 128;
  if (lane16 == 0) {
#pragma unroll
    for (int r = 0; r < 4; r++) {
      int row = 16 * w + kg * 4 + r;
      mlb[row] = m_run[r];
      mlb[64 + row] = l_run[r];
    }
  }
  float* Ob = Opart + (size_t)(head * 32 + chunk) * 64 * 128;
#pragma unroll
  for (int mt = 0; mt < 4; mt++)
#pragma unroll
    for (int dt = 0; dt < 2; dt++)
#pragma unroll
      for (int r = 0; r < 4; r++) {
        int row = mt * 16 + kg * 4 + r;
        int d = w * 32 + dt * 16 + lane16;
        Ob[(size_t)row * 128 + d] = Oac[mt][dt][r];
      }
}

// ----------------------------------------------------- axiom attention pass2
__global__ __launch_bounds__(128) void flash2_k(const float* __restrict__ Opart,
                                                const float* __restrict__ mlpart,
                                                unsigned short* __restrict__ axpre) {
  int b = blockIdx.x >> 3, n = blockIdx.x & 7;
  int d = threadIdx.x;
  float mg = -__builtin_inff();
  for (int c = 0; c < 32; ++c) mg = fmaxf(mg, mlpart[(size_t)(n * 32 + c) * 128 + b]);
  float acc = 0.f, lg = 0.f;
  for (int c = 0; c < 32; ++c) {
    const float* mlb = mlpart + (size_t)(n * 32 + c) * 128;
    float sw = expf(mlb[b] - mg);
    lg += mlb[64 + b] * sw;
    acc += sw * Opart[((size_t)(n * 32 + c) * 64 + b) * 128 + d];
  }
  axpre[b * 1024 + n * 128 + d] = f2bf(acc / lg);
}

// --------------------------------------------------------- step attention
__global__ __launch_bounds__(128) void stattn_k(const float* __restrict__ qs,
                                                const float* __restrict__ kc,
                                                const float* __restrict__ vc,
                                                unsigned short* __restrict__ stpre,
                                                int T) {
  int b = blockIdx.x >> 3, n = blockIdx.x & 7;
  int tid = threadIdx.x;
  __shared__ float sc[17];
  __shared__ float wred[2];
  int idx = b * 1024 + n * 128 + tid;
  float q = qs[idx] * SCALE_QK;
  for (int t = 0; t < T; ++t) {
    float v = q * kc[t * 65536 + idx];
#pragma unroll
    for (int m = 1; m < 64; m <<= 1) v += __shfl_xor(v, m, 64);
    __syncthreads();
    if ((tid & 63) == 0) wred[tid >> 6] = v;
    __syncthreads();
    if (tid == 0) sc[t] = wred[0] + wred[1];
  }
  __syncthreads();
  float mx = -__builtin_inff();
  for (int t = 0; t < T; ++t) mx = fmaxf(mx, sc[t]);
  float den = 0.f, o = 0.f;
  for (int t = 0; t < T; ++t) {
    float e = expf(sc[t] - mx);
    den += e;
    o += e * vc[t * 65536 + idx];
  }
  stpre[idx] = f2bf(o / den);
}

// --------------------------------------------------------- LayerNorm + GELU
__global__ __launch_bounds__(256) void ln_gelu_k(const float* __restrict__ g1,
                                                 const float* __restrict__ gam,
                                                 const float* __restrict__ bet,
                                                 unsigned short* __restrict__ xo) {
  int b = blockIdx.x;
  int tid = threadIdx.x;
  __shared__ float red[4];
  const float* row = g1 + b * 2048;
  float s = 0.f;
  for (int i = tid; i < 2048; i += 256) s += row[i];
#pragma unroll
  for (int m = 1; m < 64; m <<= 1) s += __shfl_xor(s, m, 64);
  if ((tid & 63) == 0) red[tid >> 6] = s;
  __syncthreads();
  float mean = (red[0] + red[1] + red[2] + red[3]) * (1.f / 2048.f);
  __syncthreads();
  float v = 0.f;
  for (int i = tid; i < 2048; i += 256) { float d = row[i] - mean; v += d * d; }
#pragma unroll
  for (int m = 1; m < 64; m <<= 1) v += __shfl_xor(v, m, 64);
  if ((tid & 63) == 0) red[tid >> 6] = v;
  __syncthreads();
  float var = (red[0] + red[1] + red[2] + red[3]) * (1.f / 2048.f);
  float inv = 1.0f / sqrtf(var + 1e-5f);
  for (int i = tid; i < 2048; i += 256) {
    float y = (row[i] - mean) * inv * gam[i] + bet[i];
    xo[b * 2048 + i] = f2bf(gelu_exact(y));
  }
}

// ------------------------------------------------------------- validity out
__global__ __launch_bounds__(64) void val2_k(const float* __restrict__ v1,
                                             const float* __restrict__ w2,
                                             const float* __restrict__ b2,
                                             float* __restrict__ out) {
  int b = blockIdx.x, l = threadIdx.x;
  float s = 0.f;
  for (int k = l; k < 1024; k += 64) s += v1[b * 1024 + k] * w2[k];
#pragma unroll
  for (int m = 1; m < 64; m <<= 1) s += __shfl_xor(s, m, 64);
  if (l == 0) out[b] = 1.f / (1.f + expf(-(s + b2[0])));
}

// ---------------------------------------------------------------------------
extern "C" void kernel_launch(void* const* d_in, const int* in_sizes, int n_in,
                              void* d_out, int out_size, void* d_ws, size_t ws_size,
                              hipStream_t stream) {
  (void)in_sizes; (void)n_in; (void)out_size; (void)ws_size;

  const float* conj   = (const float*)d_in[0];
  const float* aemb   = (const float*)d_in[1];
  const float* ax_in_b = (const float*)d_in[3];
  const float* ax_out_b = (const float*)d_in[5];
  const float* st_in_b = (const float*)d_in[7];
  const float* st_out_b = (const float*)d_in[9];
  const float* gen_b1 = (const float*)d_in[11];
  const float* ln_g   = (const float*)d_in[12];
  const float* ln_b   = (const float*)d_in[13];
  const float* gen_b2 = (const float*)d_in[15];
  const float* val_b1 = (const float*)d_in[17];
  const float* val_w2 = (const float*)d_in[18];
  const float* val_b2 = (const float*)d_in[19];

  // ---- workspace carve-up (~122 MB)
  size_t off = 0;
  char* wsb = (char*)d_ws;
  auto carve = [&](size_t bytes) -> void* {
    void* p = wsb + off;
    off += (bytes + 1023) & ~(size_t)1023;
    return p;
  };
  unsigned short* axw  = (unsigned short*)carve((size_t)3072 * 1024 * 2);
  unsigned short* stw  = (unsigned short*)carve((size_t)3072 * 1024 * 2);
  unsigned short* axow = (unsigned short*)carve((size_t)1024 * 1024 * 2);
  unsigned short* stow = (unsigned short*)carve((size_t)1024 * 1024 * 2);
  unsigned short* g1w  = (unsigned short*)carve((size_t)2048 * 3072 * 2);
  unsigned short* g2w  = (unsigned short*)carve((size_t)1024 * 2048 * 2);
  unsigned short* v1w  = (unsigned short*)carve((size_t)1024 * 1024 * 2);
  unsigned short* kp   = (unsigned short*)carve((size_t)16384 * 1024 * 2);
  unsigned short* vpT  = (unsigned short*)carve((size_t)16384 * 1024 * 2);
  float* kcache = (float*)carve((size_t)16 * 65536 * 4);
  float* vcache = (float*)carve((size_t)16 * 65536 * 4);
  float* Opart  = (float*)carve((size_t)8 * 32 * 64 * 128 * 4);
  float* mlpart = (float*)carve((size_t)8 * 32 * 128 * 4);
  unsigned short* comb = (unsigned short*)carve((size_t)64 * 3072 * 2);
  float* qsb  = (float*)carve((size_t)64 * 1024 * 4);
  unsigned short* qab   = (unsigned short*)carve((size_t)64 * 1024 * 2);
  unsigned short* axpre = (unsigned short*)carve((size_t)64 * 1024 * 2);
  unsigned short* stpre = (unsigned short*)carve((size_t)64 * 1024 * 2);
  float* g1f  = (float*)carve((size_t)64 * 2048 * 4);
  unsigned short* xbf = (unsigned short*)carve((size_t)64 * 2048 * 2);
  float* v1f  = (float*)carve((size_t)64 * 1024 * 4);

  // ---- weight converts (LSTM weights skipped: dead code)
  auto cvt = [&](const void* src, unsigned short* dst, size_t n) {
    int n4 = (int)(n / 4);
    int g = (n4 + 255) / 256;
    if (g > 2048) g = 2048;
    cvt_bf16_k<<<g, 256, 0, stream>>>((const float*)src, dst, n4);
  };
  cvt(d_in[2],  axw, (size_t)3072 * 1024);
  cvt(d_in[6],  stw, (size_t)3072 * 1024);
  cvt(d_in[4],  axow, (size_t)1024 * 1024);
  cvt(d_in[8],  stow, (size_t)1024 * 1024);
  cvt(d_in[10], g1w, (size_t)2048 * 3072);
  cvt(d_in[14], g2w, (size_t)1024 * 2048);
  cvt(d_in[16], v1w, (size_t)1024 * 1024);

  float* out_steps = (float*)d_out;
  init_state_k<<<256, 256, 0, stream>>>(conj, out_steps, comb);

  // axiom K/V projection (once)
  kvproj_k<<<dim3(128, 16), 256, 0, stream>>>(aemb, axw + (size_t)1024 * 1024,
                                              ax_in_b + 1024, kp, vpT);

  for (int t = 0; t < 16; ++t) {
    // qa = (state @ Wq_a^T + bq_a) * SCALE  -> bf16
    {
      GemmP p{};
      p.A = comb; p.lda = 3072; p.W = axw; p.ldw = 1024; p.bias = ax_in_b;
      p.K = 1024; p.epi = 0; p.scale = SCALE_QK; p.out_bf = qab; p.ldo = 1024;
      gemm64_k<<<16, 256, 0, stream>>>(p);
    }
    // qs | k_new | v_new = state @ st_in_w^T + st_in_b
    {
      GemmP p{};
      p.A = comb; p.lda = 3072; p.W = stw; p.ldw = 1024; p.bias = st_in_b;
      p.K = 1024; p.epi = 1;
      p.qs = qsb; p.kc = kcache + (size_t)t * 65536; p.vc = vcache + (size_t)t * 65536;
      gemm64_k<<<48, 256, 0, stream>>>(p);
    }
    // axiom attention
    flash1_k<<<256, 256, 0, stream>>>(qab, kp, vpT, Opart, mlpart);
    flash2_k<<<512, 128, 0, stream>>>(Opart, mlpart, axpre);
    // ax_out -> comb slot 1
    {
      GemmP p{};
      p.A = axpre; p.lda = 1024; p.W = axow; p.ldw = 1024; p.bias = ax_out_b;
      p.K = 1024; p.epi = 2; p.out_bf = comb + 1024; p.ldo = 3072;
      gemm64_k<<<16, 256, 0, stream>>>(p);
    }
    // step attention over cached projections (T = t+1)
    stattn_k<<<512, 128, 0, stream>>>(qsb, kcache, vcache, stpre, t + 1);
    // st_out -> comb slot 2
    {
      GemmP p{};
      p.A = stpre; p.lda = 1024; p.W = stow; p.ldw = 1024; p.bias = st_out_b;
      p.K = 1024; p.epi = 2; p.out_bf = comb + 2048; p.ldo = 3072;
      gemm64_k<<<16, 256, 0, stream>>>(p);
    }
    // gen1: comb[64,3072] @ gen_w1^T -> g1f
    {
      GemmP p{};
      p.A = comb; p.lda = 3072; p.W = g1w; p.ldw = 3072; p.bias = gen_b1;
      p.K = 3072; p.epi = 4; p.out_f32 = g1f; p.ldo_f = 2048;
      gemm64_k<<<32, 256, 0, stream>>>(p);
    }
    ln_gelu_k<<<64, 256, 0, stream>>>(g1f, ln_g, ln_b, xbf);
    // gen2: x @ gen_w2^T -> d_out slot t+1 (fp32) + comb slot 0 (bf16)
    {
      GemmP p{};
      p.A = xbf; p.lda = 2048; p.W = g2w; p.ldw = 2048; p.bias = gen_b2;
      p.K = 2048; p.epi = 5;
      p.out_f32 = out_steps + (size_t)(t + 1) * 65536; p.ldo_f = 1024;
      p.out_bf = comb; p.ldo = 3072;
      gemm64_k<<<16, 256, 0, stream>>>(p);
    }
  }

  // validity head
  {
    GemmP p{};
    p.A = comb; p.lda = 3072; p.W = v1w; p.ldw = 1024; p.bias = val_b1;
    p.K = 1024; p.epi = 3; p.out_f32 = v1f; p.ldo_f = 1024;
    gemm64_k<<<16, 256, 0, stream>>>(p);
  }
  val2_k<<<64, 64, 0, stream>>>(v1f, val_w2, val_b2, out_steps + (size_t)17 * 65536);
}

// Round 2
// 2050.880 us; speedup vs baseline: 2.8438x; 2.8438x over previous
//
#include <hip/hip_runtime.h>
#include <stdint.h>

// ---------------------------------------------------------------------------
// TheoremProver on MI355X (gfx950).
// B=64, H=1024, S_AX=16384, NH=8, DH=128, STEPS=16.
//  * LSTM weights are dead code (h/c feed only themselves) -> skipped.
//  * Axiom K/V projection hoisted out of the step loop (one MFMA GEMM).
//  * Step-attention K/V projected incrementally (1 new row-block per step).
//  * Round 2: skinny gemms restructured -- K split across the 4 waves of a
//    block + 16-col tiles => 64..256 blocks per gemm (was 16..48), LDS
//    cross-wave reduce.  Fixes the latency-bound 0.08%-occupancy gemm64.
// ---------------------------------------------------------------------------

typedef __attribute__((ext_vector_type(8))) short  bfx8;   // 8 x bf16 (4 VGPRs)
typedef __attribute__((ext_vector_type(4))) float  f32x4;

#define MFMA16(a, b, c) __builtin_amdgcn_mfma_f32_16x16x32_bf16((a), (b), (c), 0, 0, 0)

#define SCALE_QK 0.08838834764831845f  /* 1/sqrt(128) */

__device__ __forceinline__ unsigned short f2bf(float f) {
  union { float f; unsigned int u; } v; v.f = f;
  unsigned int r = (v.u + 0x7FFFu + ((v.u >> 16) & 1u)) >> 16;  // RNE
  return (unsigned short)r;
}

__device__ __forceinline__ float gelu_exact(float x) {
  return 0.5f * x * (1.0f + erff(x * 0.70710678118654752f));
}

__device__ __forceinline__ bfx8 ld8(const unsigned short* p) {
  return *reinterpret_cast<const bfx8*>(p);
}

// ---------------------------------------------------------------- fp32->bf16
// All 7 live weight tensors in ONE dispatch: blockIdx.y selects the region.
struct CvtAll {
  const float* s[7];
  unsigned short* d[7];
  int n4[7];
};

__global__ __launch_bounds__(256) void cvt_all_k(CvtAll c) {
  int reg = blockIdx.y;
  const float* s = c.s[reg];
  unsigned short* d = c.d[reg];
  int n4 = c.n4[reg];
  int stride = gridDim.x * 256;
  for (int i = blockIdx.x * 256 + threadIdx.x; i < n4; i += stride) {
    float4 v = reinterpret_cast<const float4*>(s)[i];
    ushort4 o;
    o.x = f2bf(v.x); o.y = f2bf(v.y); o.z = f2bf(v.z); o.w = f2bf(v.w);
    reinterpret_cast<ushort4*>(d)[i] = o;
  }
}

// ------------------------------------------------------------------ init
__global__ __launch_bounds__(256) void init_state_k(const float* __restrict__ conj,
                                                    float* __restrict__ out0,
                                                    unsigned short* __restrict__ comb) {
  int i = blockIdx.x * 256 + threadIdx.x;  // 65536 total
  float v = conj[i];
  out0[i] = v;
  int b = i >> 10, c = i & 1023;
  comb[b * 3072 + c] = f2bf(v);
}

// ---------------------------------------------------- axiom K/V projection
// C[16384, 2048] = axiom_emb[16384,1024] @ Wkv[2048,1024]^T + bias
// cols [0,1024) -> kp[s][c] bf16 ; cols [1024,2048) -> vpT[c-1024][s] bf16.
__global__ __launch_bounds__(256) void kvproj_k(const float* __restrict__ aemb,
                                                const unsigned short* __restrict__ Wkv,
                                                const float* __restrict__ bias,
                                                unsigned short* __restrict__ kp,
                                                unsigned short* __restrict__ vpT) {
  __shared__ __align__(16) unsigned short Asl[128 * 40];
  __shared__ __align__(16) unsigned short Bsl[128 * 40];
  int m0 = blockIdx.x * 128, n0 = blockIdx.y * 128;
  int tid = threadIdx.x;
  int w = tid >> 6, l = tid & 63;
  int wm = w >> 1, wn = w & 1;
  int lane16 = l & 15, kg = l >> 4;
  int srow = tid >> 1, shalf = tid & 1;

  const float* Ag = aemb + (size_t)(m0 + srow) * 1024 + shalf * 16;
  const unsigned short* Bg = Wkv + (size_t)(n0 + srow) * 1024 + shalf * 16;
  unsigned short* As = &Asl[srow * 40 + shalf * 16];
  unsigned short* Bs = &Bsl[srow * 40 + shalf * 16];

  f32x4 acc[4][4];
  f32x4 zz = {0.f, 0.f, 0.f, 0.f};
#pragma unroll
  for (int a = 0; a < 4; a++)
#pragma unroll
    for (int b = 0; b < 4; b++) acc[a][b] = zz;

  for (int k0 = 0; k0 < 1024; k0 += 32) {
    float4 f0 = *(const float4*)(Ag + k0);
    float4 f1 = *(const float4*)(Ag + k0 + 4);
    float4 f2 = *(const float4*)(Ag + k0 + 8);
    float4 f3 = *(const float4*)(Ag + k0 + 12);
    ushort4 u0, u1, u2, u3;
    u0.x = f2bf(f0.x); u0.y = f2bf(f0.y); u0.z = f2bf(f0.z); u0.w = f2bf(f0.w);
    u1.x = f2bf(f1.x); u1.y = f2bf(f1.y); u1.z = f2bf(f1.z); u1.w = f2bf(f1.w);
    u2.x = f2bf(f2.x); u2.y = f2bf(f2.y); u2.z = f2bf(f2.z); u2.w = f2bf(f2.w);
    u3.x = f2bf(f3.x); u3.y = f2bf(f3.y); u3.z = f2bf(f3.z); u3.w = f2bf(f3.w);
    bfx8 b0 = ld8(Bg + k0);
    bfx8 b1 = ld8(Bg + k0 + 8);

    __syncthreads();
    *(ushort4*)(As + 0) = u0;
    *(ushort4*)(As + 4) = u1;
    *(ushort4*)(As + 8) = u2;
    *(ushort4*)(As + 12) = u3;
    *reinterpret_cast<bfx8*>(Bs) = b0;
    *reinterpret_cast<bfx8*>(Bs + 8) = b1;
    __syncthreads();

    bfx8 af[4], bfr[4];
#pragma unroll
    for (int mr = 0; mr < 4; mr++)
      af[mr] = *reinterpret_cast<const bfx8*>(&Asl[(wm * 64 + mr * 16 + lane16) * 40 + kg * 8]);
#pragma unroll
    for (int nr = 0; nr < 4; nr++)
      bfr[nr] = *reinterpret_cast<const bfx8*>(&Bsl[(wn * 64 + nr * 16 + lane16) * 40 + kg * 8]);
#pragma unroll
    for (int mr = 0; mr < 4; mr++)
#pragma unroll
      for (int nr = 0; nr < 4; nr++)
        acc[mr][nr] = MFMA16(af[mr], bfr[nr], acc[mr][nr]);
  }

#pragma unroll
  for (int mr = 0; mr < 4; mr++)
#pragma unroll
    for (int nr = 0; nr < 4; nr++) {
      int rowg0 = m0 + wm * 64 + mr * 16 + kg * 4;
      int colg = n0 + wn * 64 + nr * 16 + lane16;
      float bi = bias[colg];
#pragma unroll
      for (int r = 0; r < 4; r++) {
        float v = acc[mr][nr][r] + bi;
        unsigned short bv = f2bf(v);
        int rg = rowg0 + r;
        if (colg < 1024) kp[(size_t)rg * 1024 + colg] = bv;
        else             vpT[(size_t)(colg - 1024) * 16384 + rg] = bv;
      }
    }
}

// --------------------------------------------------------- skinny M=64 GEMM
// out[64,N] = A[64,K]_bf16 @ W[N,K]_bf16^T + bias, fused epilogues.
// One block = 16 output cols; 4 waves each own K/4 (split-K within block),
// cross-wave reduce in LDS.  Two independent gemms can share one dispatch
// (GemmPair): blockIdx.x < split -> pa, else pb.
struct GemmP {
  const unsigned short* A; int lda;
  const unsigned short* W; int ldw;
  const float* bias;
  int K;
  int epi;            // 0 qa, 1 qskv-split, 2 bf16, 3 gelu->f32, 4 f32, 5 gen2
  float scale;
  unsigned short* out_bf; int ldo;
  float* out_f32; int ldo_f;
  float* qs; float* kc; float* vc;
};
struct GemmPair { GemmP pa, pb; int split; };

__global__ __launch_bounds__(256) void gemm64s_k(GemmPair pp) {
  bool first = ((int)blockIdx.x < pp.split);
  GemmP p = first ? pp.pa : pp.pb;
  int ct = first ? blockIdx.x : (blockIdx.x - pp.split);

  int w = threadIdx.x >> 6, l = threadIdx.x & 63;
  int lane16 = l & 15, kg = l >> 4;
  int col = ct * 16 + lane16;
  int kq = p.K >> 2;                 // per-wave K range
  int lda = p.lda;
  const unsigned short* Wb = p.W + (size_t)col * p.ldw + w * kq + kg * 8;
  const unsigned short* Ab = p.A + (size_t)lane16 * lda + w * kq + kg * 8;

  f32x4 zz = {0.f, 0.f, 0.f, 0.f};
  f32x4 acc0 = zz, acc1 = zz, acc2 = zz, acc3 = zz;
#pragma unroll 4
  for (int k = 0; k < kq; k += 32) {
    bfx8 bw = ld8(Wb + k);
    acc0 = MFMA16(ld8(Ab + k), bw, acc0);
    acc1 = MFMA16(ld8(Ab + 16 * lda + k), bw, acc1);
    acc2 = MFMA16(ld8(Ab + 32 * lda + k), bw, acc2);
    acc3 = MFMA16(ld8(Ab + 48 * lda + k), bw, acc3);
  }

  // cross-wave reduce: red[w*4+mt][lane]
  __shared__ f32x4 red[16][64];
  red[w * 4 + 0][l] = acc0;
  red[w * 4 + 1][l] = acc1;
  red[w * 4 + 2][l] = acc2;
  red[w * 4 + 3][l] = acc3;
  __syncthreads();
  // wave w finalizes row-tile mt == w
  f32x4 fin = red[0 * 4 + w][l];
  fin += red[1 * 4 + w][l];
  fin += red[2 * 4 + w][l];
  fin += red[3 * 4 + w][l];

  float bi = p.bias[col];
#pragma unroll
  for (int r = 0; r < 4; ++r) {
    int row = w * 16 + kg * 4 + r;
    float v = fin[r] + bi;
    switch (p.epi) {
      case 0:  // qa: (x+b)*scale -> bf16
        p.out_bf[(size_t)row * p.ldo + col] = f2bf(v * p.scale);
        break;
      case 1:  // qskv: split q (f32), k_new, v_new (f32 caches)
        if (col < 1024)       p.qs[row * 1024 + col] = v;
        else if (col < 2048)  p.kc[row * 1024 + col - 1024] = v;
        else                  p.vc[row * 1024 + col - 2048] = v;
        break;
      case 2:  // bf16 out (into comb slots)
        p.out_bf[(size_t)row * p.ldo + col] = f2bf(v);
        break;
      case 3:  // gelu -> f32 (validity hidden)
        p.out_f32[(size_t)row * p.ldo_f + col] = gelu_exact(v);
        break;
      case 4:  // f32 out (gen1 pre-LN)
        p.out_f32[(size_t)row * p.ldo_f + col] = v;
        break;
      case 5:  // gen2: f32 -> d_out step slot, bf16 -> comb slot 0
        p.out_f32[(size_t)row * p.ldo_f + col] = v;
        p.out_bf[(size_t)row * p.ldo + col] = f2bf(v);
        break;
    }
  }
}

// ----------------------------------------------------- axiom attention pass1
// Per (head, 512-key chunk): flash partial (m, l, O[64,128]) with MFMA.
__global__ __launch_bounds__(256) void flash1_k(const unsigned short* __restrict__ qa,
                                                const unsigned short* __restrict__ kp,
                                                const unsigned short* __restrict__ vpT,
                                                float* __restrict__ Opart,
                                                float* __restrict__ mlpart) {
  int head = blockIdx.x >> 5;
  int chunk = blockIdx.x & 31;
  int w = threadIdx.x >> 6, l = threadIdx.x & 63;
  int lane16 = l & 15, kg = l >> 4;

  __shared__ __align__(16) unsigned short P_lds[64 * 72];
  __shared__ float alpha_lds[64];

  bfx8 qf[4];
  {
    const unsigned short* qb = qa + (size_t)(16 * w + lane16) * 1024 + head * 128 + kg * 8;
#pragma unroll
    for (int kk = 0; kk < 4; kk++) qf[kk] = ld8(qb + kk * 32);
  }
  float m_run[4], l_run[4];
#pragma unroll
  for (int r = 0; r < 4; r++) { m_run[r] = -__builtin_inff(); l_run[r] = 0.f; }
  f32x4 zz = {0.f, 0.f, 0.f, 0.f};
  f32x4 Oac[4][2];
#pragma unroll
  for (int mt = 0; mt < 4; mt++) { Oac[mt][0] = zz; Oac[mt][1] = zz; }

  for (int kb = 0; kb < 8; ++kb) {
    int key0 = chunk * 512 + kb * 64;
    f32x4 sa[4] = {zz, zz, zz, zz};
#pragma unroll
    for (int kt = 0; kt < 4; kt++) {
      const unsigned short* kbp = kp + (size_t)(key0 + kt * 16 + lane16) * 1024 + head * 128 + kg * 8;
#pragma unroll
      for (int kk = 0; kk < 4; kk++) sa[kt] = MFMA16(qf[kk], ld8(kbp + kk * 32), sa[kt]);
    }
    __syncthreads();
#pragma unroll
    for (int r = 0; r < 4; r++) {
      float mx = fmaxf(fmaxf(sa[0][r], sa[1][r]), fmaxf(sa[2][r], sa[3][r]));
#pragma unroll
      for (int m = 1; m < 16; m <<= 1) mx = fmaxf(mx, __shfl_xor(mx, m, 64));
      float mnew = fmaxf(m_run[r], mx);
      float al = expf(m_run[r] - mnew);
      int row = 16 * w + kg * 4 + r;
      float rs = 0.f;
#pragma unroll
      for (int kt = 0; kt < 4; kt++) {
        float pv = expf(sa[kt][r] - mnew);
        rs += pv;
        P_lds[row * 72 + kt * 16 + lane16] = f2bf(pv);
      }
#pragma unroll
      for (int m = 1; m < 16; m <<= 1) rs += __shfl_xor(rs, m, 64);
      l_run[r] = l_run[r] * al + rs;
      m_run[r] = mnew;
      if (lane16 == 0) alpha_lds[row] = al;
    }
    __syncthreads();
#pragma unroll
    for (int mt = 0; mt < 4; mt++)
#pragma unroll
      for (int r = 0; r < 4; r++) {
        float al = alpha_lds[mt * 16 + kg * 4 + r];
        Oac[mt][0][r] *= al;
        Oac[mt][1][r] *= al;
      }
    int d0 = w * 32;
#pragma unroll
    for (int ks = 0; ks < 2; ks++) {
      bfx8 pf[4];
#pragma unroll
      for (int mt = 0; mt < 4; mt++)
        pf[mt] = *reinterpret_cast<const bfx8*>(&P_lds[(mt * 16 + lane16) * 72 + ks * 32 + kg * 8]);
#pragma unroll
      for (int dt = 0; dt < 2; dt++) {
        int d = d0 + dt * 16 + lane16;
        bfx8 vf = ld8(vpT + (size_t)(head * 128 + d) * 16384 + key0 + ks * 32 + kg * 8);
#pragma unroll
        for (int mt = 0; mt < 4; mt++) Oac[mt][dt] = MFMA16(pf[mt], vf, Oac[mt][dt]);
      }
    }
  }
  float* mlb = mlpart + (size_t)(head * 32 + chunk) * 128;
  if (lane16 == 0) {
#pragma unroll
    for (int r = 0; r < 4; r++) {
      int row = 16 * w + kg * 4 + r;
      mlb[row] = m_run[r];
      mlb[64 + row] = l_run[r];
    }
  }
  float* Ob = Opart + (size_t)(head * 32 + chunk) * 64 * 128;
#pragma unroll
  for (int mt = 0; mt < 4; mt++)
#pragma unroll
    for (int dt = 0; dt < 2; dt++)
#pragma unroll
      for (int r = 0; r < 4; r++) {
        int row = mt * 16 + kg * 4 + r;
        int d = w * 32 + dt * 16 + lane16;
        Ob[(size_t)row * 128 + d] = Oac[mt][dt][r];
      }
}

// ----------------------------------------------------- axiom attention pass2
__global__ __launch_bounds__(128) void flash2_k(const float* __restrict__ Opart,
                                                const float* __restrict__ mlpart,
                                                unsigned short* __restrict__ axpre) {
  int b = blockIdx.x >> 3, n = blockIdx.x & 7;
  int d = threadIdx.x;
  float mg = -__builtin_inff();
  for (int c = 0; c < 32; ++c) mg = fmaxf(mg, mlpart[(size_t)(n * 32 + c) * 128 + b]);
  float acc = 0.f, lg = 0.f;
  for (int c = 0; c < 32; ++c) {
    const float* mlb = mlpart + (size_t)(n * 32 + c) * 128;
    float sw = expf(mlb[b] - mg);
    lg += mlb[64 + b] * sw;
    acc += sw * Opart[((size_t)(n * 32 + c) * 64 + b) * 128 + d];
  }
  axpre[b * 1024 + n * 128 + d] = f2bf(acc / lg);
}

// --------------------------------------------------------- step attention
__global__ __launch_bounds__(128) void stattn_k(const float* __restrict__ qs,
                                                const float* __restrict__ kc,
                                                const float* __restrict__ vc,
                                                unsigned short* __restrict__ stpre,
                                                int T) {
  int b = blockIdx.x >> 3, n = blockIdx.x & 7;
  int tid = threadIdx.x;
  __shared__ float sc[17];
  __shared__ float wred[2];
  int idx = b * 1024 + n * 128 + tid;
  float q = qs[idx] * SCALE_QK;
  for (int t = 0; t < T; ++t) {
    float v = q * kc[t * 65536 + idx];
#pragma unroll
    for (int m = 1; m < 64; m <<= 1) v += __shfl_xor(v, m, 64);
    __syncthreads();
    if ((tid & 63) == 0) wred[tid >> 6] = v;
    __syncthreads();
    if (tid == 0) sc[t] = wred[0] + wred[1];
  }
  __syncthreads();
  float mx = -__builtin_inff();
  for (int t = 0; t < T; ++t) mx = fmaxf(mx, sc[t]);
  float den = 0.f, o = 0.f;
  for (int t = 0; t < T; ++t) {
    float e = expf(sc[t] - mx);
    den += e;
    o += e * vc[t * 65536 + idx];
  }
  stpre[idx] = f2bf(o / den);
}

// --------------------------------------------------------- LayerNorm + GELU
__global__ __launch_bounds__(256) void ln_gelu_k(const float* __restrict__ g1,
                                                 const float* __restrict__ gam,
                                                 const float* __restrict__ bet,
                                                 unsigned short* __restrict__ xo) {
  int b = blockIdx.x;
  int tid = threadIdx.x;
  __shared__ float red[4];
  const float* row = g1 + b * 2048;
  float s = 0.f;
  for (int i = tid; i < 2048; i += 256) s += row[i];
#pragma unroll
  for (int m = 1; m < 64; m <<= 1) s += __shfl_xor(s, m, 64);
  if ((tid & 63) == 0) red[tid >> 6] = s;
  __syncthreads();
  float mean = (red[0] + red[1] + red[2] + red[3]) * (1.f / 2048.f);
  __syncthreads();
  float v = 0.f;
  for (int i = tid; i < 2048; i += 256) { float d = row[i] - mean; v += d * d; }
#pragma unroll
  for (int m = 1; m < 64; m <<= 1) v += __shfl_xor(v, m, 64);
  if ((tid & 63) == 0) red[tid >> 6] = v;
  __syncthreads();
  float var = (red[0] + red[1] + red[2] + red[3]) * (1.f / 2048.f);
  float inv = 1.0f / sqrtf(var + 1e-5f);
  for (int i = tid; i < 2048; i += 256) {
    float y = (row[i] - mean) * inv * gam[i] + bet[i];
    xo[b * 2048 + i] = f2bf(gelu_exact(y));
  }
}

// ------------------------------------------------------------- validity out
__global__ __launch_bounds__(64) void val2_k(const float* __restrict__ v1,
                                             const float* __restrict__ w2,
                                             const float* __restrict__ b2,
                                             float* __restrict__ out) {
  int b = blockIdx.x, l = threadIdx.x;
  float s = 0.f;
  for (int k = l; k < 1024; k += 64) s += v1[b * 1024 + k] * w2[k];
#pragma unroll
  for (int m = 1; m < 64; m <<= 1) s += __shfl_xor(s, m, 64);
  if (l == 0) out[b] = 1.f / (1.f + expf(-(s + b2[0])));
}

// ---------------------------------------------------------------------------
extern "C" void kernel_launch(void* const* d_in, const int* in_sizes, int n_in,
                              void* d_out, int out_size, void* d_ws, size_t ws_size,
                              hipStream_t stream) {
  (void)in_sizes; (void)n_in; (void)out_size; (void)ws_size;

  const float* conj   = (const float*)d_in[0];
  const float* aemb   = (const float*)d_in[1];
  const float* ax_in_b = (const float*)d_in[3];
  const float* ax_out_b = (const float*)d_in[5];
  const float* st_in_b = (const float*)d_in[7];
  const float* st_out_b = (const float*)d_in[9];
  const float* gen_b1 = (const float*)d_in[11];
  const float* ln_g   = (const float*)d_in[12];
  const float* ln_b   = (const float*)d_in[13];
  const float* gen_b2 = (const float*)d_in[15];
  const float* val_b1 = (const float*)d_in[17];
  const float* val_w2 = (const float*)d_in[18];
  const float* val_b2 = (const float*)d_in[19];

  // ---- workspace carve-up (~124 MB)
  size_t off = 0;
  char* wsb = (char*)d_ws;
  auto carve = [&](size_t bytes) -> void* {
    void* p = wsb + off;
    off += (bytes + 1023) & ~(size_t)1023;
    return p;
  };
  unsigned short* axw  = (unsigned short*)carve((size_t)3072 * 1024 * 2);
  unsigned short* stw  = (unsigned short*)carve((size_t)3072 * 1024 * 2);
  unsigned short* axow = (unsigned short*)carve((size_t)1024 * 1024 * 2);
  unsigned short* stow = (unsigned short*)carve((size_t)1024 * 1024 * 2);
  unsigned short* g1w  = (unsigned short*)carve((size_t)2048 * 3072 * 2);
  unsigned short* g2w  = (unsigned short*)carve((size_t)1024 * 2048 * 2);
  unsigned short* v1w  = (unsigned short*)carve((size_t)1024 * 1024 * 2);
  unsigned short* kp   = (unsigned short*)carve((size_t)16384 * 1024 * 2);
  unsigned short* vpT  = (unsigned short*)carve((size_t)16384 * 1024 * 2);
  float* kcache = (float*)carve((size_t)16 * 65536 * 4);
  float* vcache = (float*)carve((size_t)16 * 65536 * 4);
  float* Opart  = (float*)carve((size_t)8 * 32 * 64 * 128 * 4);
  float* mlpart = (float*)carve((size_t)8 * 32 * 128 * 4);
  unsigned short* comb = (unsigned short*)carve((size_t)64 * 3072 * 2);
  float* qsb  = (float*)carve((size_t)64 * 1024 * 4);
  unsigned short* qab   = (unsigned short*)carve((size_t)64 * 1024 * 2);
  unsigned short* axpre = (unsigned short*)carve((size_t)64 * 1024 * 2);
  unsigned short* stpre = (unsigned short*)carve((size_t)64 * 1024 * 2);
  float* g1f  = (float*)carve((size_t)64 * 2048 * 4);
  unsigned short* xbf = (unsigned short*)carve((size_t)64 * 2048 * 2);
  float* v1f  = (float*)carve((size_t)64 * 1024 * 4);

  // ---- weight converts, one dispatch (LSTM weights skipped: dead code)
  {
    CvtAll c;
    c.s[0] = (const float*)d_in[2];  c.d[0] = axw;  c.n4[0] = 3072 * 1024 / 4;
    c.s[1] = (const float*)d_in[6];  c.d[1] = stw;  c.n4[1] = 3072 * 1024 / 4;
    c.s[2] = (const float*)d_in[4];  c.d[2] = axow; c.n4[2] = 1024 * 1024 / 4;
    c.s[3] = (const float*)d_in[8];  c.d[3] = stow; c.n4[3] = 1024 * 1024 / 4;
    c.s[4] = (const float*)d_in[10]; c.d[4] = g1w;  c.n4[4] = 2048 * 3072 / 4;
    c.s[5] = (const float*)d_in[14]; c.d[5] = g2w;  c.n4[5] = 1024 * 2048 / 4;
    c.s[6] = (const float*)d_in[16]; c.d[6] = v1w;  c.n4[6] = 1024 * 1024 / 4;
    cvt_all_k<<<dim3(512, 7), 256, 0, stream>>>(c);
  }

  float* out_steps = (float*)d_out;
  init_state_k<<<256, 256, 0, stream>>>(conj, out_steps, comb);

  // axiom K/V projection (once)
  kvproj_k<<<dim3(128, 16), 256, 0, stream>>>(aemb, axw + (size_t)1024 * 1024,
                                              ax_in_b + 1024, kp, vpT);

  auto launch_pair = [&](const GemmP& a, int blka, const GemmP& b, int blkb) {
    GemmPair pp;
    pp.pa = a; pp.pb = b; pp.split = blka;
    gemm64s_k<<<blka + blkb, 256, 0, stream>>>(pp);
  };
  auto launch_one = [&](const GemmP& a, int blka) {
    GemmPair pp;
    pp.pa = a; pp.pb = a; pp.split = blka;
    gemm64s_k<<<blka, 256, 0, stream>>>(pp);
  };

  for (int t = 0; t < 16; ++t) {
    // G1: qa = (state@Wq_a^T+b)*scale  ||  qs|k_new|v_new = state@st_in_w^T+b
    {
      GemmP pa{}, pb{};
      pa.A = comb; pa.lda = 3072; pa.W = axw; pa.ldw = 1024; pa.bias = ax_in_b;
      pa.K = 1024; pa.epi = 0; pa.scale = SCALE_QK; pa.out_bf = qab; pa.ldo = 1024;
      pb.A = comb; pb.lda = 3072; pb.W = stw; pb.ldw = 1024; pb.bias = st_in_b;
      pb.K = 1024; pb.epi = 1;
      pb.qs = qsb; pb.kc = kcache + (size_t)t * 65536; pb.vc = vcache + (size_t)t * 65536;
      launch_pair(pa, 64, pb, 192);
    }
    // axiom attention
    flash1_k<<<256, 256, 0, stream>>>(qab, kp, vpT, Opart, mlpart);
    flash2_k<<<512, 128, 0, stream>>>(Opart, mlpart, axpre);
    // step attention over cached projections (T = t+1)
    stattn_k<<<512, 128, 0, stream>>>(qsb, kcache, vcache, stpre, t + 1);
    // G2: ax_out -> comb slot 1  ||  st_out -> comb slot 2
    {
      GemmP pa{}, pb{};
      pa.A = axpre; pa.lda = 1024; pa.W = axow; pa.ldw = 1024; pa.bias = ax_out_b;
      pa.K = 1024; pa.epi = 2; pa.out_bf = comb + 1024; pa.ldo = 3072;
      pb.A = stpre; pb.lda = 1024; pb.W = stow; pb.ldw = 1024; pb.bias = st_out_b;
      pb.K = 1024; pb.epi = 2; pb.out_bf = comb + 2048; pb.ldo = 3072;
      launch_pair(pa, 64, pb, 64);
    }
    // gen1: comb[64,3072] @ gen_w1^T -> g1f
    {
      GemmP p{};
      p.A = comb; p.lda = 3072; p.W = g1w; p.ldw = 3072; p.bias = gen_b1;
      p.K = 3072; p.epi = 4; p.out_f32 = g1f; p.ldo_f = 2048;
      launch_one(p, 128);
    }
    ln_gelu_k<<<64, 256, 0, stream>>>(g1f, ln_g, ln_b, xbf);
    // gen2: x @ gen_w2^T -> d_out slot t+1 (fp32) + comb slot 0 (bf16)
    {
      GemmP p{};
      p.A = xbf; p.lda = 2048; p.W = g2w; p.ldw = 2048; p.bias = gen_b2;
      p.K = 2048; p.epi = 5;
      p.out_f32 = out_steps + (size_t)(t + 1) * 65536; p.ldo_f = 1024;
      p.out_bf = comb; p.ldo = 3072;
      launch_one(p, 64);
    }
  }

  // validity head
  {
    GemmP p{};
    p.A = comb; p.lda = 3072; p.W = v1w; p.ldw = 1024; p.bias = val_b1;
    p.K = 1024; p.epi = 3; p.out_f32 = v1f; p.ldo_f = 1024;
    launch_one(p, 64);
  }
  val2_k<<<64, 64, 0, stream>>>(v1f, val_w2, val_b2, out_steps + (size_t)17 * 65536);
}

// Round 4
// 1931.399 us; speedup vs baseline: 3.0198x; 1.0619x over previous
//
#include <hip/hip_runtime.h>
#include <stdint.h>

// ---------------------------------------------------------------------------
// TheoremProver on MI355X (gfx950).
// B=64, H=1024, S_AX=16384, NH=8, DH=128, STEPS=16.
//  * LSTM weights are dead code (h/c feed only themselves) -> skipped.
//  * Axiom K/V projection hoisted out of the step loop (one MFMA GEMM).
//  * Step-attention K/V projected incrementally (1 new row-block per step).
//  * R2: skinny gemms: K split across 4 waves + 16-col tiles (latency fix).
//  * R3: flash1 one-chunk-per-block two-phase softmax (regs->LDS P, 1 barrier,
//    512 blocks); kvproj reads pre-converted bf16 A + XCD swizzle;
//    flash2+stattn fused into one dispatch.
//  * R4: identical resubmit (R3 bench was GPUAcquisitionTimeout).
// ---------------------------------------------------------------------------

typedef __attribute__((ext_vector_type(8))) short  bfx8;   // 8 x bf16 (4 VGPRs)
typedef __attribute__((ext_vector_type(4))) float  f32x4;

#define MFMA16(a, b, c) __builtin_amdgcn_mfma_f32_16x16x32_bf16((a), (b), (c), 0, 0, 0)

#define SCALE_QK 0.08838834764831845f  /* 1/sqrt(128) */

__device__ __forceinline__ unsigned short f2bf(float f) {
  union { float f; unsigned int u; } v; v.f = f;
  unsigned int r = (v.u + 0x7FFFu + ((v.u >> 16) & 1u)) >> 16;  // RNE
  return (unsigned short)r;
}

__device__ __forceinline__ float gelu_exact(float x) {
  return 0.5f * x * (1.0f + erff(x * 0.70710678118654752f));
}

__device__ __forceinline__ bfx8 ld8(const unsigned short* p) {
  return *reinterpret_cast<const bfx8*>(p);
}

// ---------------------------------------------------------------- fp32->bf16
// All 7 live weight tensors + axiom_emb in ONE dispatch.
struct CvtAll {
  const float* s[8];
  unsigned short* d[8];
  int n4[8];
};

__global__ __launch_bounds__(256) void cvt_all_k(CvtAll c) {
  int reg = blockIdx.y;
  const float* s = c.s[reg];
  unsigned short* d = c.d[reg];
  int n4 = c.n4[reg];
  int stride = gridDim.x * 256;
  for (int i = blockIdx.x * 256 + threadIdx.x; i < n4; i += stride) {
    float4 v = reinterpret_cast<const float4*>(s)[i];
    ushort4 o;
    o.x = f2bf(v.x); o.y = f2bf(v.y); o.z = f2bf(v.z); o.w = f2bf(v.w);
    reinterpret_cast<ushort4*>(d)[i] = o;
  }
}

// ------------------------------------------------------------------ init
__global__ __launch_bounds__(256) void init_state_k(const float* __restrict__ conj,
                                                    float* __restrict__ out0,
                                                    unsigned short* __restrict__ comb) {
  int i = blockIdx.x * 256 + threadIdx.x;  // 65536 total
  float v = conj[i];
  out0[i] = v;
  int b = i >> 10, c = i & 1023;
  comb[b * 3072 + c] = f2bf(v);
}

// ---------------------------------------------------- axiom K/V projection
// C[16384, 2048] = aembh[16384,1024]_bf16 @ Wkv[2048,1024]^T + bias
// cols [0,1024) -> kp[s][c] bf16 ; cols [1024,2048) -> vpT[c-1024][s] bf16.
// 1D grid 2048, XCD-chunked swizzle (2048 % 8 == 0 -> bijective).
__global__ __launch_bounds__(256) void kvproj_k(const unsigned short* __restrict__ aembh,
                                                const unsigned short* __restrict__ Wkv,
                                                const float* __restrict__ bias,
                                                unsigned short* __restrict__ kp,
                                                unsigned short* __restrict__ vpT) {
  __shared__ __align__(16) unsigned short Asl[128 * 40];
  __shared__ __align__(16) unsigned short Bsl[128 * 40];
  int lin = ((int)blockIdx.x & 7) * 256 + ((int)blockIdx.x >> 3);  // XCD swizzle
  int m0 = (lin >> 4) * 128, n0 = (lin & 15) * 128;
  int tid = threadIdx.x;
  int w = tid >> 6, l = tid & 63;
  int wm = w >> 1, wn = w & 1;
  int lane16 = l & 15, kg = l >> 4;
  int srow = tid >> 1, shalf = tid & 1;

  const unsigned short* Ag = aembh + (size_t)(m0 + srow) * 1024 + shalf * 16;
  const unsigned short* Bg = Wkv + (size_t)(n0 + srow) * 1024 + shalf * 16;
  unsigned short* As = &Asl[srow * 40 + shalf * 16];
  unsigned short* Bs = &Bsl[srow * 40 + shalf * 16];

  f32x4 acc[4][4];
  f32x4 zz = {0.f, 0.f, 0.f, 0.f};
#pragma unroll
  for (int a = 0; a < 4; a++)
#pragma unroll
    for (int b = 0; b < 4; b++) acc[a][b] = zz;

  for (int k0 = 0; k0 < 1024; k0 += 32) {
    bfx8 a0 = ld8(Ag + k0);
    bfx8 a1 = ld8(Ag + k0 + 8);
    bfx8 b0 = ld8(Bg + k0);
    bfx8 b1 = ld8(Bg + k0 + 8);

    __syncthreads();
    *reinterpret_cast<bfx8*>(As) = a0;
    *reinterpret_cast<bfx8*>(As + 8) = a1;
    *reinterpret_cast<bfx8*>(Bs) = b0;
    *reinterpret_cast<bfx8*>(Bs + 8) = b1;
    __syncthreads();

    bfx8 af[4], bfr[4];
#pragma unroll
    for (int mr = 0; mr < 4; mr++)
      af[mr] = *reinterpret_cast<const bfx8*>(&Asl[(wm * 64 + mr * 16 + lane16) * 40 + kg * 8]);
#pragma unroll
    for (int nr = 0; nr < 4; nr++)
      bfr[nr] = *reinterpret_cast<const bfx8*>(&Bsl[(wn * 64 + nr * 16 + lane16) * 40 + kg * 8]);
#pragma unroll
    for (int mr = 0; mr < 4; mr++)
#pragma unroll
      for (int nr = 0; nr < 4; nr++)
        acc[mr][nr] = MFMA16(af[mr], bfr[nr], acc[mr][nr]);
  }

#pragma unroll
  for (int mr = 0; mr < 4; mr++)
#pragma unroll
    for (int nr = 0; nr < 4; nr++) {
      int rowg0 = m0 + wm * 64 + mr * 16 + kg * 4;
      int colg = n0 + wn * 64 + nr * 16 + lane16;
      float bi = bias[colg];
      if (colg < 1024) {
#pragma unroll
        for (int r = 0; r < 4; r++)
          kp[(size_t)(rowg0 + r) * 1024 + colg] = f2bf(acc[mr][nr][r] + bi);
      } else {
        // 4 consecutive s-rows for one v-col -> one 8B store
        ushort4 pk;
        pk.x = f2bf(acc[mr][nr][0] + bi);
        pk.y = f2bf(acc[mr][nr][1] + bi);
        pk.z = f2bf(acc[mr][nr][2] + bi);
        pk.w = f2bf(acc[mr][nr][3] + bi);
        *reinterpret_cast<ushort4*>(&vpT[(size_t)(colg - 1024) * 16384 + rowg0]) = pk;
      }
    }
}

// --------------------------------------------------------- skinny M=64 GEMM
// out[64,N] = A[64,K]_bf16 @ W[N,K]_bf16^T + bias, fused epilogues.
// One block = 16 output cols; 4 waves each own K/4 (split-K within block),
// cross-wave reduce in LDS.  Two independent gemms share one dispatch.
struct GemmP {
  const unsigned short* A; int lda;
  const unsigned short* W; int ldw;
  const float* bias;
  int K;
  int epi;            // 0 qa, 1 qskv-split, 2 bf16, 3 gelu->f32, 4 f32, 5 gen2
  float scale;
  unsigned short* out_bf; int ldo;
  float* out_f32; int ldo_f;
  float* qs; float* kc; float* vc;
};
struct GemmPair { GemmP pa, pb; int split; };

__global__ __launch_bounds__(256) void gemm64s_k(GemmPair pp) {
  bool first = ((int)blockIdx.x < pp.split);
  GemmP p = first ? pp.pa : pp.pb;
  int ct = first ? blockIdx.x : (blockIdx.x - pp.split);

  int w = threadIdx.x >> 6, l = threadIdx.x & 63;
  int lane16 = l & 15, kg = l >> 4;
  int col = ct * 16 + lane16;
  int kq = p.K >> 2;                 // per-wave K range
  int lda = p.lda;
  const unsigned short* Wb = p.W + (size_t)col * p.ldw + w * kq + kg * 8;
  const unsigned short* Ab = p.A + (size_t)lane16 * lda + w * kq + kg * 8;

  f32x4 zz = {0.f, 0.f, 0.f, 0.f};
  f32x4 acc0 = zz, acc1 = zz, acc2 = zz, acc3 = zz;
#pragma unroll 4
  for (int k = 0; k < kq; k += 32) {
    bfx8 bw = ld8(Wb + k);
    acc0 = MFMA16(ld8(Ab + k), bw, acc0);
    acc1 = MFMA16(ld8(Ab + 16 * lda + k), bw, acc1);
    acc2 = MFMA16(ld8(Ab + 32 * lda + k), bw, acc2);
    acc3 = MFMA16(ld8(Ab + 48 * lda + k), bw, acc3);
  }

  __shared__ f32x4 red[16][64];
  red[w * 4 + 0][l] = acc0;
  red[w * 4 + 1][l] = acc1;
  red[w * 4 + 2][l] = acc2;
  red[w * 4 + 3][l] = acc3;
  __syncthreads();
  f32x4 fin = red[0 * 4 + w][l];
  fin += red[1 * 4 + w][l];
  fin += red[2 * 4 + w][l];
  fin += red[3 * 4 + w][l];

  float bi = p.bias[col];
#pragma unroll
  for (int r = 0; r < 4; ++r) {
    int row = w * 16 + kg * 4 + r;
    float v = fin[r] + bi;
    switch (p.epi) {
      case 0:
        p.out_bf[(size_t)row * p.ldo + col] = f2bf(v * p.scale);
        break;
      case 1:
        if (col < 1024)       p.qs[row * 1024 + col] = v;
        else if (col < 2048)  p.kc[row * 1024 + col - 1024] = v;
        else                  p.vc[row * 1024 + col - 2048] = v;
        break;
      case 2:
        p.out_bf[(size_t)row * p.ldo + col] = f2bf(v);
        break;
      case 3:
        p.out_f32[(size_t)row * p.ldo_f + col] = gelu_exact(v);
        break;
      case 4:
        p.out_f32[(size_t)row * p.ldo_f + col] = v;
        break;
      case 5:
        p.out_f32[(size_t)row * p.ldo_f + col] = v;
        p.out_bf[(size_t)row * p.ldo + col] = f2bf(v);
        break;
    }
  }
}

// ----------------------------------------------------- axiom attention pass1
// One block = (head, 256-key chunk).  Scores in registers, two-phase softmax,
// single barrier, P in LDS (stride 264 shorts: 132 dwords % 32 == 4 -> ~free).
__global__ __launch_bounds__(256) void flash1_k(const unsigned short* __restrict__ qa,
                                                const unsigned short* __restrict__ kp,
                                                const unsigned short* __restrict__ vpT,
                                                float* __restrict__ Opart,
                                                float* __restrict__ mlpart) {
  int head = blockIdx.x >> 6;
  int chunk = blockIdx.x & 63;
  int key0 = chunk * 256;
  int w = threadIdx.x >> 6, l = threadIdx.x & 63;
  int lane16 = l & 15, kg = l >> 4;

  __shared__ __align__(16) unsigned short P_lds[64 * 264];

  // Q fragments: wave w owns q-rows [16w, 16w+16)
  bfx8 qf[4];
  {
    const unsigned short* qb = qa + (size_t)(16 * w + lane16) * 1024 + head * 128 + kg * 8;
#pragma unroll
    for (int kk = 0; kk < 4; kk++) qf[kk] = ld8(qb + kk * 32);
  }

  // ---- QK^T over the whole chunk: 16 key-tiles, scores live in regs
  f32x4 zz = {0.f, 0.f, 0.f, 0.f};
  f32x4 sa[16];
#pragma unroll
  for (int kt = 0; kt < 16; kt++) {
    const unsigned short* kbp = kp + (size_t)(key0 + kt * 16 + lane16) * 1024 + head * 128 + kg * 8;
    f32x4 s = zz;
#pragma unroll
    for (int kk = 0; kk < 4; kk++) s = MFMA16(qf[kk], ld8(kbp + kk * 32), s);
    sa[kt] = s;
  }

  // ---- single-pass softmax per row (lane holds keys kt*16+lane16, row kg*4+r)
  float mrow[4], lrow[4];
#pragma unroll
  for (int r = 0; r < 4; r++) {
    float mx = sa[0][r];
#pragma unroll
    for (int kt = 1; kt < 16; kt++) mx = fmaxf(mx, sa[kt][r]);
#pragma unroll
    for (int m = 1; m < 16; m <<= 1) mx = fmaxf(mx, __shfl_xor(mx, m, 64));
    int row = 16 * w + kg * 4 + r;
    float rs = 0.f;
#pragma unroll
    for (int kt = 0; kt < 16; kt++) {
      float pv = expf(sa[kt][r] - mx);
      rs += pv;
      P_lds[row * 264 + kt * 16 + lane16] = f2bf(pv);
    }
#pragma unroll
    for (int m = 1; m < 16; m <<= 1) rs += __shfl_xor(rs, m, 64);
    mrow[r] = mx;
    lrow[r] = rs;
  }
  __syncthreads();

  // ---- P @ V: wave w owns d-cols [32w, 32w+32), all 64 rows
  f32x4 Oac[4][2];
#pragma unroll
  for (int mt = 0; mt < 4; mt++) { Oac[mt][0] = zz; Oac[mt][1] = zz; }
#pragma unroll
  for (int ks = 0; ks < 8; ks++) {
    bfx8 pf[4];
#pragma unroll
    for (int mt = 0; mt < 4; mt++)
      pf[mt] = *reinterpret_cast<const bfx8*>(&P_lds[(mt * 16 + lane16) * 264 + ks * 32 + kg * 8]);
#pragma unroll
    for (int dt = 0; dt < 2; dt++) {
      int d = w * 32 + dt * 16 + lane16;
      bfx8 vf = ld8(vpT + (size_t)(head * 128 + d) * 16384 + key0 + ks * 32 + kg * 8);
#pragma unroll
      for (int mt = 0; mt < 4; mt++) Oac[mt][dt] = MFMA16(pf[mt], vf, Oac[mt][dt]);
    }
  }

  // ---- write partials
  float* mlb = mlpart + (size_t)(head * 64 + chunk) * 128;
  if (lane16 == 0) {
#pragma unroll
    for (int r = 0; r < 4; r++) {
      int row = 16 * w + kg * 4 + r;
      mlb[row] = mrow[r];
      mlb[64 + row] = lrow[r];
    }
  }
  float* Ob = Opart + (size_t)(head * 64 + chunk) * 64 * 128;
#pragma unroll
  for (int mt = 0; mt < 4; mt++)
#pragma unroll
    for (int dt = 0; dt < 2; dt++)
#pragma unroll
      for (int r = 0; r < 4; r++)
        Ob[(size_t)(mt * 16 + kg * 4 + r) * 128 + w * 32 + dt * 16 + lane16] = Oac[mt][dt][r];
}

// --------------------------- fused: flash2 (combine) + step attention
__global__ __launch_bounds__(128) void f2st_k(const float* __restrict__ Opart,
                                              const float* __restrict__ mlpart,
                                              unsigned short* __restrict__ axpre,
                                              const float* __restrict__ qs,
                                              const float* __restrict__ kc,
                                              const float* __restrict__ vc,
                                              unsigned short* __restrict__ stpre,
                                              int T) {
  if ((int)blockIdx.x < 512) {
    // ---- flash2: combine 64 chunk partials
    int b = blockIdx.x >> 3, n = blockIdx.x & 7;
    int d = threadIdx.x;
    float mg = -__builtin_inff();
    for (int c = 0; c < 64; ++c) mg = fmaxf(mg, mlpart[(size_t)(n * 64 + c) * 128 + b]);
    float acc = 0.f, lg = 0.f;
    for (int c = 0; c < 64; ++c) {
      const float* mlb = mlpart + (size_t)(n * 64 + c) * 128;
      float sw = expf(mlb[b] - mg);
      lg += mlb[64 + b] * sw;
      acc += sw * Opart[((size_t)(n * 64 + c) * 64 + b) * 128 + d];
    }
    axpre[b * 1024 + n * 128 + d] = f2bf(acc / lg);
  } else {
    // ---- step attention over cached K/V projections
    int bi = blockIdx.x - 512;
    int b = bi >> 3, n = bi & 7;
    int tid = threadIdx.x;
    __shared__ float sc[17];
    __shared__ float wred[2];
    int idx = b * 1024 + n * 128 + tid;
    float q = qs[idx] * SCALE_QK;
    for (int t = 0; t < T; ++t) {
      float v = q * kc[t * 65536 + idx];
#pragma unroll
      for (int m = 1; m < 64; m <<= 1) v += __shfl_xor(v, m, 64);
      __syncthreads();
      if ((tid & 63) == 0) wred[tid >> 6] = v;
      __syncthreads();
      if (tid == 0) sc[t] = wred[0] + wred[1];
    }
    __syncthreads();
    float mx = -__builtin_inff();
    for (int t = 0; t < T; ++t) mx = fmaxf(mx, sc[t]);
    float den = 0.f, o = 0.f;
    for (int t = 0; t < T; ++t) {
      float e = expf(sc[t] - mx);
      den += e;
      o += e * vc[t * 65536 + idx];
    }
    stpre[idx] = f2bf(o / den);
  }
}

// --------------------------------------------------------- LayerNorm + GELU
__global__ __launch_bounds__(256) void ln_gelu_k(const float* __restrict__ g1,
                                                 const float* __restrict__ gam,
                                                 const float* __restrict__ bet,
                                                 unsigned short* __restrict__ xo) {
  int b = blockIdx.x;
  int tid = threadIdx.x;
  __shared__ float red[4];
  const float* row = g1 + b * 2048;
  float s = 0.f;
  for (int i = tid; i < 2048; i += 256) s += row[i];
#pragma unroll
  for (int m = 1; m < 64; m <<= 1) s += __shfl_xor(s, m, 64);
  if ((tid & 63) == 0) red[tid >> 6] = s;
  __syncthreads();
  float mean = (red[0] + red[1] + red[2] + red[3]) * (1.f / 2048.f);
  __syncthreads();
  float v = 0.f;
  for (int i = tid; i < 2048; i += 256) { float d = row[i] - mean; v += d * d; }
#pragma unroll
  for (int m = 1; m < 64; m <<= 1) v += __shfl_xor(v, m, 64);
  if ((tid & 63) == 0) red[tid >> 6] = v;
  __syncthreads();
  float var = (red[0] + red[1] + red[2] + red[3]) * (1.f / 2048.f);
  float inv = 1.0f / sqrtf(var + 1e-5f);
  for (int i = tid; i < 2048; i += 256) {
    float y = (row[i] - mean) * inv * gam[i] + bet[i];
    xo[b * 2048 + i] = f2bf(gelu_exact(y));
  }
}

// ------------------------------------------------------------- validity out
__global__ __launch_bounds__(64) void val2_k(const float* __restrict__ v1,
                                             const float* __restrict__ w2,
                                             const float* __restrict__ b2,
                                             float* __restrict__ out) {
  int b = blockIdx.x, l = threadIdx.x;
  float s = 0.f;
  for (int k = l; k < 1024; k += 64) s += v1[b * 1024 + k] * w2[k];
#pragma unroll
  for (int m = 1; m < 64; m <<= 1) s += __shfl_xor(s, m, 64);
  if (l == 0) out[b] = 1.f / (1.f + expf(-(s + b2[0])));
}

// ---------------------------------------------------------------------------
extern "C" void kernel_launch(void* const* d_in, const int* in_sizes, int n_in,
                              void* d_out, int out_size, void* d_ws, size_t ws_size,
                              hipStream_t stream) {
  (void)in_sizes; (void)n_in; (void)out_size; (void)ws_size;

  const float* conj   = (const float*)d_in[0];
  const float* aemb   = (const float*)d_in[1];
  const float* ax_in_b = (const float*)d_in[3];
  const float* ax_out_b = (const float*)d_in[5];
  const float* st_in_b = (const float*)d_in[7];
  const float* st_out_b = (const float*)d_in[9];
  const float* gen_b1 = (const float*)d_in[11];
  const float* ln_g   = (const float*)d_in[12];
  const float* ln_b   = (const float*)d_in[13];
  const float* gen_b2 = (const float*)d_in[15];
  const float* val_b1 = (const float*)d_in[17];
  const float* val_w2 = (const float*)d_in[18];
  const float* val_b2 = (const float*)d_in[19];

  // ---- workspace carve-up (~175 MB)
  size_t off = 0;
  char* wsb = (char*)d_ws;
  auto carve = [&](size_t bytes) -> void* {
    void* p = wsb + off;
    off += (bytes + 1023) & ~(size_t)1023;
    return p;
  };
  unsigned short* axw  = (unsigned short*)carve((size_t)3072 * 1024 * 2);
  unsigned short* stw  = (unsigned short*)carve((size_t)3072 * 1024 * 2);
  unsigned short* axow = (unsigned short*)carve((size_t)1024 * 1024 * 2);
  unsigned short* stow = (unsigned short*)carve((size_t)1024 * 1024 * 2);
  unsigned short* g1w  = (unsigned short*)carve((size_t)2048 * 3072 * 2);
  unsigned short* g2w  = (unsigned short*)carve((size_t)1024 * 2048 * 2);
  unsigned short* v1w  = (unsigned short*)carve((size_t)1024 * 1024 * 2);
  unsigned short* aembh = (unsigned short*)carve((size_t)16384 * 1024 * 2);
  unsigned short* kp   = (unsigned short*)carve((size_t)16384 * 1024 * 2);
  unsigned short* vpT  = (unsigned short*)carve((size_t)16384 * 1024 * 2);
  float* kcache = (float*)carve((size_t)16 * 65536 * 4);
  float* vcache = (float*)carve((size_t)16 * 65536 * 4);
  float* Opart  = (float*)carve((size_t)8 * 64 * 64 * 128 * 4);
  float* mlpart = (float*)carve((size_t)8 * 64 * 128 * 4);
  unsigned short* comb = (unsigned short*)carve((size_t)64 * 3072 * 2);
  float* qsb  = (float*)carve((size_t)64 * 1024 * 4);
  unsigned short* qab   = (unsigned short*)carve((size_t)64 * 1024 * 2);
  unsigned short* axpre = (unsigned short*)carve((size_t)64 * 1024 * 2);
  unsigned short* stpre = (unsigned short*)carve((size_t)64 * 1024 * 2);
  float* g1f  = (float*)carve((size_t)64 * 2048 * 4);
  unsigned short* xbf = (unsigned short*)carve((size_t)64 * 2048 * 2);
  float* v1f  = (float*)carve((size_t)64 * 1024 * 4);

  // ---- converts, one dispatch (LSTM weights skipped: dead code)
  {
    CvtAll c;
    c.s[0] = (const float*)d_in[2];  c.d[0] = axw;   c.n4[0] = 3072 * 1024 / 4;
    c.s[1] = (const float*)d_in[6];  c.d[1] = stw;   c.n4[1] = 3072 * 1024 / 4;
    c.s[2] = (const float*)d_in[4];  c.d[2] = axow;  c.n4[2] = 1024 * 1024 / 4;
    c.s[3] = (const float*)d_in[8];  c.d[3] = stow;  c.n4[3] = 1024 * 1024 / 4;
    c.s[4] = (const float*)d_in[10]; c.d[4] = g1w;   c.n4[4] = 2048 * 3072 / 4;
    c.s[5] = (const float*)d_in[14]; c.d[5] = g2w;   c.n4[5] = 1024 * 2048 / 4;
    c.s[6] = (const float*)d_in[16]; c.d[6] = v1w;   c.n4[6] = 1024 * 1024 / 4;
    c.s[7] = aemb;                   c.d[7] = aembh; c.n4[7] = 16384 * 1024 / 4;
    cvt_all_k<<<dim3(512, 8), 256, 0, stream>>>(c);
  }

  float* out_steps = (float*)d_out;
  init_state_k<<<256, 256, 0, stream>>>(conj, out_steps, comb);

  // axiom K/V projection (once)
  kvproj_k<<<2048, 256, 0, stream>>>(aembh, axw + (size_t)1024 * 1024,
                                     ax_in_b + 1024, kp, vpT);

  auto launch_pair = [&](const GemmP& a, int blka, const GemmP& b, int blkb) {
    GemmPair pp;
    pp.pa = a; pp.pb = b; pp.split = blka;
    gemm64s_k<<<blka + blkb, 256, 0, stream>>>(pp);
  };
  auto launch_one = [&](const GemmP& a, int blka) {
    GemmPair pp;
    pp.pa = a; pp.pb = a; pp.split = blka;
    gemm64s_k<<<blka, 256, 0, stream>>>(pp);
  };

  for (int t = 0; t < 16; ++t) {
    // G1: qa = (state@Wq_a^T+b)*scale  ||  qs|k_new|v_new = state@st_in_w^T+b
    {
      GemmP pa{}, pb{};
      pa.A = comb; pa.lda = 3072; pa.W = axw; pa.ldw = 1024; pa.bias = ax_in_b;
      pa.K = 1024; pa.epi = 0; pa.scale = SCALE_QK; pa.out_bf = qab; pa.ldo = 1024;
      pb.A = comb; pb.lda = 3072; pb.W = stw; pb.ldw = 1024; pb.bias = st_in_b;
      pb.K = 1024; pb.epi = 1;
      pb.qs = qsb; pb.kc = kcache + (size_t)t * 65536; pb.vc = vcache + (size_t)t * 65536;
      launch_pair(pa, 64, pb, 192);
    }
    // axiom attention pass 1
    flash1_k<<<512, 256, 0, stream>>>(qab, kp, vpT, Opart, mlpart);
    // flash2 combine || step attention (T = t+1)
    f2st_k<<<1024, 128, 0, stream>>>(Opart, mlpart, axpre, qsb, kcache, vcache,
                                     stpre, t + 1);
    // G2: ax_out -> comb slot 1  ||  st_out -> comb slot 2
    {
      GemmP pa{}, pb{};
      pa.A = axpre; pa.lda = 1024; pa.W = axow; pa.ldw = 1024; pa.bias = ax_out_b;
      pa.K = 1024; pa.epi = 2; pa.out_bf = comb + 1024; pa.ldo = 3072;
      pb.A = stpre; pb.lda = 1024; pb.W = stow; pb.ldw = 1024; pb.bias = st_out_b;
      pb.K = 1024; pb.epi = 2; pb.out_bf = comb + 2048; pb.ldo = 3072;
      launch_pair(pa, 64, pb, 64);
    }
    // gen1: comb[64,3072] @ gen_w1^T -> g1f
    {
      GemmP p{};
      p.A = comb; p.lda = 3072; p.W = g1w; p.ldw = 3072; p.bias = gen_b1;
      p.K = 3072; p.epi = 4; p.out_f32 = g1f; p.ldo_f = 2048;
      launch_one(p, 128);
    }
    ln_gelu_k<<<64, 256, 0, stream>>>(g1f, ln_g, ln_b, xbf);
    // gen2: x @ gen_w2^T -> d_out slot t+1 (fp32) + comb slot 0 (bf16)
    {
      GemmP p{};
      p.A = xbf; p.lda = 2048; p.W = g2w; p.ldw = 2048; p.bias = gen_b2;
      p.K = 2048; p.epi = 5;
      p.out_f32 = out_steps + (size_t)(t + 1) * 65536; p.ldo_f = 1024;
      p.out_bf = comb; p.ldo = 3072;
      launch_one(p, 64);
    }
  }

  // validity head
  {
    GemmP p{};
    p.A = comb; p.lda = 3072; p.W = v1w; p.ldw = 1024; p.bias = val_b1;
    p.K = 1024; p.epi = 3; p.out_f32 = v1f; p.ldo_f = 1024;
    launch_one(p, 64);
  }
  val2_k<<<64, 64, 0, stream>>>(v1f, val_w2, val_b2, out_steps + (size_t)17 * 65536);
}